// Round 9
// baseline (380.137 us; speedup 1.0000x reference)
//
#include <hip/hip_runtime.h>
#include <hip/hip_bf16.h>

// Problem constants (GraphGRUCell_62019327754706)
// DTYPES (settled r4/r5): all float tensors FP32 in and out. int32 edges.
// r6: never clamp launch_bounds waves -> spills.
// r8: 4 nodes/wave @ block=256 => VGPR 64, no spill.
// r9: 8 nodes/wave => spills -> never.
// r11: half-wave node pairing REGRESSED. XCD swizzle WORKED -> keep.
// r12: dense union-range tiling + no-max softmax -> fused 196us. KEEP.
// r13: single-pass padded u16 bins -> total 333, fused 190 = BEST.
// r14/r15: fp16+fdot2 container-failed TWICE -> fdot2 BLACKLISTED.
// r16/r17: quarter-wave phase B CLOSED (granularity x ILP worse for deg~32).
// r18: "r13 phase B" + {wbar-for-syncthreads, unroll4} = 228us, VALU 48%,
//      bank-conf 2552. Outer __syncthreads are NOT pure overhead: they keep
//      the block's 4 waves phase-converged (L1/L2 gather locality + better
//      scheduling). wbar-everywhere REJECTED.
// r19 (this): A/B arm X = r13-exact + ONLY unroll-4 pragmas in fused dense
//      loops. X~190 -> barrier was r18's culprit (unroll4 innocent);
//      X~228 -> unroll4 culprit. Single-variable vs both r13 and r18.
#define BB 4
#define NN 20000
#define UU 64
#define EE 640000
#define FF 65              // U + D
#define SCALE_F 0.125f     // 1/sqrt(64)
#define PREP_BLOCKS 2500   // (B*N)/32
#define SCAT_BLOCKS 2500   // EE/256

typedef unsigned short u16;
typedef unsigned long long u64;

static inline size_t align_up(size_t x) { return (x + 255) & ~(size_t)255; }

__device__ __forceinline__ float u2f(unsigned int u) { return __uint_as_float(u); }
__device__ __forceinline__ u16 f2bf(float f) {
    __hip_bfloat16 h = __float2bfloat16(f);
    return *reinterpret_cast<u16*>(&h);
}

// ---------------- fat kernel: prep (even blocks) || bin-scatter (odd blocks)
// prep: k,v (bf16) + mask, 8 nodes/wave. scatter: bins[dst*cap+pos]=src.
// r13-exact.
__global__ __launch_bounds__(256) void prep_scatter_kernel(
    const float* __restrict__ state, const float* __restrict__ inputs,
    const float* __restrict__ Wk, const float* __restrict__ bk,
    const float* __restrict__ Wv, const float* __restrict__ bv,
    u16* __restrict__ kbuf, u16* __restrict__ vbuf,
    unsigned char* __restrict__ maskb,
    const int* __restrict__ edst, const int* __restrict__ esrc,
    int* __restrict__ counts, u16* __restrict__ bins, int cap) {
    int role = blockIdx.x & 1;
    int sub  = blockIdx.x >> 1;
    if (role) {                               // ---- bin-scatter role
        int e = sub * 256 + threadIdx.x;
        if (e < EE) {
            int d = edst[e], s = esrc[e];
            if ((unsigned)d < (unsigned)NN && (unsigned)s < (unsigned)NN) {
                int pos = atomicAdd(&counts[d], 1);
                if (pos < cap) bins[d * cap + pos] = (u16)s;  // clamp: no OOB
            }
        }
        return;
    }
    // ---- prep role
    int w = threadIdx.x >> 6, lane = threadIdx.x & 63;
    int gb = (sub * 4 + w) * 8;               // 8 nodes per wave
    __shared__ float xs[4][8][66];
#pragma unroll
    for (int j = 0; j < 8; ++j) {
        int g = gb + j;
        xs[w][j][lane] = state[(size_t)g * UU + lane];
        if (lane == 0) xs[w][j][64] = inputs[g];
    }
    __syncthreads();                          // uniform (all prep threads reach)

    float ak[8], av[8];
#pragma unroll
    for (int j = 0; j < 8; ++j) { ak[j] = 0.f; av[j] = 0.f; }
    for (int f = 0; f < FF; ++f) {            // weight loaded once, 8 nodes reuse
        float wk = Wk[f * UU + lane], wv = Wv[f * UU + lane];
#pragma unroll
        for (int j = 0; j < 8; ++j) {
            float xv = xs[w][j][f];
            ak[j] += xv * wk; av[j] += xv * wv;
        }
    }
    float bkl = bk[lane], bvl = bv[lane];
#pragma unroll
    for (int j = 0; j < 8; ++j) {
        int g = gb + j;
        kbuf[(size_t)g * UU + lane] = f2bf(ak[j] + bkl);
        vbuf[(size_t)g * UU + lane] = f2bf(av[j] + bvl);
        if (lane == 0) maskb[g] = (xs[w][j][58] != 0.0f) ? 1 : 0;
    }
}

// -------------------- fused: 4 nodes/wave, union tiling over bins, GRU
// r13-exact except: unroll-4 pragmas on the three dense f-loops (the A/B).
__global__ __launch_bounds__(256) void fused_fast(
    const float* __restrict__ state, const float* __restrict__ inputs,
    const float* __restrict__ Wq, const float* __restrict__ bq,
    const float* __restrict__ Ws, const float* __restrict__ bs,
    const float* __restrict__ W1, const float* __restrict__ b1,
    const float* __restrict__ W2, const float* __restrict__ b2,
    const u16* __restrict__ kbuf, const u16* __restrict__ vbuf,
    const unsigned char* __restrict__ maskb,
    const int* __restrict__ counts, const u16* __restrict__ bins, int cap,
    float* __restrict__ out) {
    int w = threadIdx.x >> 6, lane = threadIdx.x & 63;
    int hl = lane & 31, hf = lane >> 5;

    // XCD-aware swizzle: batch b pinned to XCDs {2b, 2b+1} (r11: FETCH -29%).
    // grid = 5000 = 625*8, dispatch round-robins XCD = bid%8 -> bijective.
    int bid = blockIdx.x;
    int xcd = bid & 7;
    int b   = xcd >> 1;                            // batch 0..3
    int ib  = ((bid >> 3) << 1) | (xcd & 1);       // block-in-batch 0..1249
    int gb  = b * NN + ib * 16 + w * 4;            // 4 consecutive nodes/wave

    __shared__ float xs[4][4][66];            // x rows; later h2 rows
    __shared__ float qs[4][4][68];            // q rows (68: 4-bank row skew)
    __shared__ u64   pl[4][64];               // per-wave {srow,p} publish

#pragma unroll
    for (int j = 0; j < 4; ++j) {
        int g = gb + j;
        xs[w][j][lane] = state[(size_t)g * UU + lane];
        if (lane == 0) xs[w][j][64] = inputs[g];
    }
    __syncthreads();                          // A (uniform)

    // q (pre-scaled) + sproj for 4 nodes; weight value loaded once
    float aq[4], as_[4];
#pragma unroll
    for (int j = 0; j < 4; ++j) { aq[j] = 0.f; as_[j] = 0.f; }
#pragma unroll 4
    for (int f = 0; f < FF; ++f) {
        float wq = Wq[f * UU + lane], ws = Ws[f * UU + lane];
#pragma unroll
        for (int j = 0; j < 4; ++j) {
            float xv = xs[w][j][f];
            aq[j] += xv * wq; as_[j] += xv * ws;
        }
    }
    float bql = bq[lane], bsl = bs[lane];
#pragma unroll
    for (int j = 0; j < 4; ++j) {
        as_[j] += bsl;
        qs[w][j][lane] = (aq[j] + bql) * SCALE_F;
    }
    __syncthreads();                          // B (uniform)

    bool mg[4];
#pragma unroll
    for (int j = 0; j < 4; ++j) mg[j] = (xs[w][j][58] != 0.0f);

    const unsigned char* mb = maskb + (size_t)b * NN;
    const u16* kb = kbuf + (size_t)b * NN * UU;
    const u16* vb = vbuf + (size_t)b * NN * UU;
    int nb = gb - b * NN;                     // node base within batch

    // virtual concatenated span over the 4 nodes' bins
    int cum[5]; cum[0] = 0;
    int ebase[4];
#pragma unroll
    for (int j = 0; j < 4; ++j) {
        int dg = counts[nb + j];
        dg = min(max(dg, 0), cap);
        if (!mg[j]) dg = 0;                   // masked dst: skip entire bin
        cum[j + 1] = cum[j] + dg;
        ebase[j] = (nb + j) * cap - cum[j];   // bins addr = ebase[j] + i
    }
    int total = cum[4];

    // accumulators: lane hl holds channels (2hl, 2hl+1) of its half's slots
    float acE[4], acO[4], l[4];
#pragma unroll
    for (int j = 0; j < 4; ++j) { acE[j] = 0.f; acO[j] = 0.f; l[j] = 0.f; }

    const unsigned* vbw = (const unsigned*)vb; // bf16 channel-pair view

#pragma unroll 1
    for (int tbase = 0; tbase < total; tbase += 64) {
        // ---- phase A: lane = edge in dense union tile
        int i = tbase + lane;
        float p = 0.f; int srow = 0;
        if (i < total) {
            int jl = (i >= cum[1]) + (i >= cum[2]) + (i >= cum[3]);
            int s = bins[ebase[jl] + i];
            if (mb[s]) {
                srow = s;
                const uint4* kp = (const uint4*)(kb + ((size_t)s << 6));
                const float* qrow = &qs[w][0][0] + jl * 68;  // per-lane node q
                float d0 = 0.f, d1 = 0.f, d2 = 0.f, d3 = 0.f;
#pragma unroll
                for (int c = 0; c < 8; ++c) {
                    uint4 kk = kp[c];
                    const float4 qa = *(const float4*)&qrow[c * 8];
                    const float4 qc = *(const float4*)&qrow[c * 8 + 4];
                    d0 += u2f(kk.x << 16) * qa.x; d1 += u2f(kk.x & 0xFFFF0000u) * qa.y;
                    d2 += u2f(kk.y << 16) * qa.z; d3 += u2f(kk.y & 0xFFFF0000u) * qa.w;
                    d0 += u2f(kk.z << 16) * qc.x; d1 += u2f(kk.z & 0xFFFF0000u) * qc.y;
                    d2 += u2f(kk.w << 16) * qc.z; d3 += u2f(kk.w & 0xFFFF0000u) * qc.w;
                }
                float sc = (d0 + d1) + (d2 + d3);
                p = __expf(sc);               // no-max softmax: scores ~N(0,1)
            }
        }
        pl[w][lane] = ((u64)(unsigned)srow << 32) | (u64)__float_as_uint(p);
        __builtin_amdgcn_wave_barrier();

        // ---- phase B: half-wave slot pairing; lane hl = channels 2hl,2hl+1
#pragma unroll
        for (int j = 0; j < 4; ++j) {
            int lo = max(cum[j], tbase);
            int hi = min(cum[j + 1], tbase + 64);
#pragma unroll 1
            for (int s0 = lo; s0 < hi; s0 += 8) {
#pragma unroll
                for (int k2 = 0; k2 < 4; ++k2) {
                    int ss = s0 + 2 * k2 + hf;
                    int sidx = min(ss, hi - 1) - tbase;
                    u64 pk = pl[w][sidx];     // broadcast per half
                    float pj = (ss < hi) ? u2f((unsigned)pk) : 0.f;
                    unsigned sj = (unsigned)(pk >> 32);
                    unsigned v2 = vbw[(sj << 5) | (unsigned)hl];  // 2 channels
                    acE[j] += pj * u2f(v2 << 16);
                    acO[j] += pj * u2f(v2 & 0xFFFF0000u);
                    l[j]   += pj;
                }
            }
        }
        __builtin_amdgcn_wave_barrier();
    }

    // finalize: combine halves, remap channel-pair layout -> lane=channel
#pragma unroll
    for (int j = 0; j < 4; ++j) {
        float lj = l[j]   + __shfl_xor(l[j],   32, 64);
        float aE = acE[j] + __shfl_xor(acE[j], 32, 64);
        float aO = acO[j] + __shfl_xor(acO[j], 32, 64);
        float vE = __shfl(aE, lane >> 1, 64);
        float vO = __shfl(aO, lane >> 1, 64);
        float acc = (lane & 1) ? vO : vE;
        float agg = (lj > 0.f) ? acc / fmaxf(lj, 1e-16f) : 0.f;
        float h2 = mg[j] ? (agg + as_[j]) : xs[w][j][lane];  // masked: pass h
        xs[w][j][lane] = h2;                  // own slot; [64]=xin preserved
    }
    __syncthreads();                          // C (uniform)

    // GRU: value = sigmoid([xin,h2]@W1+b1), c = tanh([xin,r*h2]@W2+b2)
    float xin[4];
#pragma unroll
    for (int j = 0; j < 4; ++j) xin[j] = xs[w][j][64];
    float a1v[4], a2v[4];
#pragma unroll
    for (int j = 0; j < 4; ++j) { a1v[j] = xin[j] * W1[lane]; a2v[j] = xin[j] * W1[UU + lane]; }
#pragma unroll 4
    for (int f = 0; f < UU; ++f) {
        float w1a = W1[(f + 1) * 128 + lane], w1b = W1[(f + 1) * 128 + UU + lane];
#pragma unroll
        for (int j = 0; j < 4; ++j) {
            float hv = xs[w][j][f];
            a1v[j] += hv * w1a; a2v[j] += hv * w1b;
        }
    }
    float b1a = b1[lane], b1b = b1[UU + lane];
    float rst[4], z[4];
#pragma unroll
    for (int j = 0; j < 4; ++j) {
        rst[j] = 1.f / (1.f + __expf(-(a1v[j] + b1a)));
        z[j]   = 1.f / (1.f + __expf(-(a2v[j] + b1b)));
        qs[w][j][lane] = rst[j] * xs[w][j][lane];   // reset*h2
    }
    __syncthreads();                          // D (uniform)

    float a3v[4];
#pragma unroll
    for (int j = 0; j < 4; ++j) a3v[j] = xin[j] * W2[lane];
#pragma unroll 4
    for (int f = 0; f < UU; ++f) {
        float w2v = W2[(f + 1) * UU + lane];
#pragma unroll
        for (int j = 0; j < 4; ++j) a3v[j] += qs[w][j][f] * w2v;
    }
    float b2l = b2[lane];
#pragma unroll
    for (int j = 0; j < 4; ++j) {
        float a = a3v[j] + b2l;
        float aa = fabsf(a), tt = __expf(-2.f * aa);
        float c = copysignf((1.f - tt) / (1.f + tt), a);
        float h2v_ = xs[w][j][lane];
        out[(size_t)(gb + j) * UU + lane] = (1.f - z[j]) * h2v_ + z[j] * c;
    }
}

// ------------------------------------------------------------------- launch
extern "C" void kernel_launch(void* const* d_in, const int* in_sizes, int n_in,
                              void* d_out, int out_size, void* d_ws, size_t ws_size,
                              hipStream_t stream) {
    const float* inputs = (const float*)d_in[0];
    const float* state  = (const float*)d_in[1];
    if (in_sizes[0] != BB * NN) { inputs = (const float*)d_in[1]; state = (const float*)d_in[0]; }
    const int*   esrc   = (const int*)d_in[2];
    const int*   edst   = (const int*)d_in[3];
    const float* Wq = (const float*)d_in[4];
    const float* bq = (const float*)d_in[5];
    const float* Wk = (const float*)d_in[6];
    const float* bk = (const float*)d_in[7];
    const float* Wv = (const float*)d_in[8];
    const float* bv = (const float*)d_in[9];
    const float* Ws = (const float*)d_in[10];
    const float* bs = (const float*)d_in[11];
    const float* W1 = (const float*)d_in[12];
    const float* b1 = (const float*)d_in[13];
    const float* W2 = (const float*)d_in[14];
    const float* b2 = (const float*)d_in[15];
    float* out = (float*)d_out;

    // workspace carve: fixed parts first, bins take the remainder (cap sized
    // from ws_size; cap=64 needs exactly the r8-proven footprint, cap<=128).
    char* base = (char*)d_ws;
    size_t ofs = 0;
    int* counts = (int*)(base + ofs); ofs = align_up(ofs + (size_t)NN * 4);
    unsigned char* maskb = (unsigned char*)(base + ofs); ofs = align_up(ofs + (size_t)BB * NN);
    u16* kbuf = (u16*)(base + ofs); ofs = align_up(ofs + (size_t)BB * NN * UU * 2);
    u16* vbuf = (u16*)(base + ofs); ofs = align_up(ofs + (size_t)BB * NN * UU * 2);
    u16* bins = (u16*)(base + ofs);
    size_t avail = (ws_size > ofs) ? (ws_size - ofs) : 0;
    int cap = (int)(avail / ((size_t)NN * 2));
    if (cap > 128) cap = 128;
    if (cap < 64)  cap = 64;   // r8-proven budget guarantees this fits
    (void)n_in; (void)out_size;

    hipMemsetAsync(counts, 0, (size_t)NN * 4, stream);
    prep_scatter_kernel<<<PREP_BLOCKS + SCAT_BLOCKS, 256, 0, stream>>>(
        state, inputs, Wk, bk, Wv, bv, kbuf, vbuf, maskb,
        edst, esrc, counts, bins, cap);
    fused_fast<<<(BB * NN) / 16, 256, 0, stream>>>(state, inputs, Wq, bq,
                                                   Ws, bs, W1, b1, W2, b2,
                                                   kbuf, vbuf, maskb,
                                                   counts, bins, cap, out);
}

// Round 10
// 365.986 us; speedup vs baseline: 1.0387x; 1.0387x over previous
//
#include <hip/hip_runtime.h>
#include <hip/hip_bf16.h>

// Problem constants (GraphGRUCell_62019327754706)
// DTYPES (settled r4/r5): all float tensors FP32 in and out. int32 edges.
// r6: never clamp launch_bounds waves -> spills.
// r8: 4 nodes/wave @ block=256 => VGPR 64, no spill.
// r9: 8 nodes/wave => spills -> never.
// r11: half-wave node pairing REGRESSED. XCD swizzle WORKED -> keep.
// r12: dense union-range tiling + no-max softmax -> KEEP.
// r13: single-pass padded u16 bins -> total 333, fused 190 = BEST base.
// r14/r15: fp16+fdot2 container-failed TWICE -> fdot2 BLACKLISTED.
// r16/r17: quarter-wave phase B CLOSED.
// r18/r19 A/B: "#pragma unroll 4" on dense f-loops is the 190->230 culprit
//      (defeats compiler pipelining; VALU 59->47%). NEVER re-add. Barrier
//      swap innocent. Dense proj/GRU = ~55-60% of fused VALU work.
// r20 (this): r13-exact structure + packed fp32 FMA (v_pk_fma_f32 via clang
//      f32x2 ext_vector, default -ffp-contract=fast): proj 8->4 FMA/f,
//      GRU-W1 8->4/f, GRU-W2 4->2/f, prep 16->8/f, phaseA 16->8/c,
//      phaseB 2->1/k2. Loads/schedule/barriers unchanged.
#define BB 4
#define NN 20000
#define UU 64
#define EE 640000
#define FF 65              // U + D
#define SCALE_F 0.125f     // 1/sqrt(64)
#define PREP_BLOCKS 2500   // (B*N)/32
#define SCAT_BLOCKS 2500   // EE/256

typedef unsigned short u16;
typedef unsigned long long u64;
typedef float f2 __attribute__((ext_vector_type(2)));

static inline size_t align_up(size_t x) { return (x + 255) & ~(size_t)255; }

__device__ __forceinline__ float u2f(unsigned int u) { return __uint_as_float(u); }
__device__ __forceinline__ u16 f2bf(float f) {
    __hip_bfloat16 h = __float2bfloat16(f);
    return *reinterpret_cast<u16*>(&h);
}
__device__ __forceinline__ f2 mkf2(float a, float b) { f2 r; r.x = a; r.y = b; return r; }
// bf16 pair (packed u32) -> f2 {lo, hi}
__device__ __forceinline__ f2 bf2f2(unsigned v) {
    return mkf2(u2f(v << 16), u2f(v & 0xFFFF0000u));
}

// ---------------- fat kernel: prep (even blocks) || bin-scatter (odd blocks)
// prep: k,v (bf16) + mask, 8 nodes/wave. scatter: bins[dst*cap+pos]=src.
__global__ __launch_bounds__(256) void prep_scatter_kernel(
    const float* __restrict__ state, const float* __restrict__ inputs,
    const float* __restrict__ Wk, const float* __restrict__ bk,
    const float* __restrict__ Wv, const float* __restrict__ bv,
    u16* __restrict__ kbuf, u16* __restrict__ vbuf,
    unsigned char* __restrict__ maskb,
    const int* __restrict__ edst, const int* __restrict__ esrc,
    int* __restrict__ counts, u16* __restrict__ bins, int cap) {
    int role = blockIdx.x & 1;
    int sub  = blockIdx.x >> 1;
    if (role) {                               // ---- bin-scatter role
        int e = sub * 256 + threadIdx.x;
        if (e < EE) {
            int d = edst[e], s = esrc[e];
            if ((unsigned)d < (unsigned)NN && (unsigned)s < (unsigned)NN) {
                int pos = atomicAdd(&counts[d], 1);
                if (pos < cap) bins[d * cap + pos] = (u16)s;  // clamp: no OOB
            }
        }
        return;
    }
    // ---- prep role
    int w = threadIdx.x >> 6, lane = threadIdx.x & 63;
    int gb = (sub * 4 + w) * 8;               // 8 nodes per wave
    __shared__ float xs[4][8][66];
#pragma unroll
    for (int j = 0; j < 8; ++j) {
        int g = gb + j;
        xs[w][j][lane] = state[(size_t)g * UU + lane];
        if (lane == 0) xs[w][j][64] = inputs[g];
    }
    __syncthreads();                          // uniform (all prep threads reach)

    f2 akv[8];                                // {ak, av} packed per node
#pragma unroll
    for (int j = 0; j < 8; ++j) akv[j] = mkf2(0.f, 0.f);
    for (int f = 0; f < FF; ++f) {            // weight loaded once, 8 nodes reuse
        f2 wkv = mkf2(Wk[f * UU + lane], Wv[f * UU + lane]);
#pragma unroll
        for (int j = 0; j < 8; ++j) {
            float xv = xs[w][j][f];
            akv[j] += mkf2(xv, xv) * wkv;     // v_pk_fma_f32
        }
    }
    float bkl = bk[lane], bvl = bv[lane];
#pragma unroll
    for (int j = 0; j < 8; ++j) {
        int g = gb + j;
        kbuf[(size_t)g * UU + lane] = f2bf(akv[j].x + bkl);
        vbuf[(size_t)g * UU + lane] = f2bf(akv[j].y + bvl);
        if (lane == 0) maskb[g] = (xs[w][j][58] != 0.0f) ? 1 : 0;
    }
}

// -------------------- fused: 4 nodes/wave, union tiling over bins, GRU
__global__ __launch_bounds__(256) void fused_fast(
    const float* __restrict__ state, const float* __restrict__ inputs,
    const float* __restrict__ Wq, const float* __restrict__ bq,
    const float* __restrict__ Ws, const float* __restrict__ bs,
    const float* __restrict__ W1, const float* __restrict__ b1,
    const float* __restrict__ W2, const float* __restrict__ b2,
    const u16* __restrict__ kbuf, const u16* __restrict__ vbuf,
    const unsigned char* __restrict__ maskb,
    const int* __restrict__ counts, const u16* __restrict__ bins, int cap,
    float* __restrict__ out) {
    int w = threadIdx.x >> 6, lane = threadIdx.x & 63;
    int hl = lane & 31, hf = lane >> 5;

    // XCD-aware swizzle: batch b pinned to XCDs {2b, 2b+1} (r11: FETCH -29%).
    // grid = 5000 = 625*8, dispatch round-robins XCD = bid%8 -> bijective.
    int bid = blockIdx.x;
    int xcd = bid & 7;
    int b   = xcd >> 1;                            // batch 0..3
    int ib  = ((bid >> 3) << 1) | (xcd & 1);       // block-in-batch 0..1249
    int gb  = b * NN + ib * 16 + w * 4;            // 4 consecutive nodes/wave

    __shared__ float xs[4][4][66];            // x rows; later h2 rows
    __shared__ float qs[4][4][68];            // q rows (68: 4-bank row skew)
    __shared__ u64   pl[4][64];               // per-wave {srow,p} publish

#pragma unroll
    for (int j = 0; j < 4; ++j) {
        int g = gb + j;
        xs[w][j][lane] = state[(size_t)g * UU + lane];
        if (lane == 0) xs[w][j][64] = inputs[g];
    }
    __syncthreads();                          // A (uniform)

    // q (pre-scaled) + sproj for 4 nodes; {aq,as} packed -> v_pk_fma_f32
    f2 aqs[4];
#pragma unroll
    for (int j = 0; j < 4; ++j) aqs[j] = mkf2(0.f, 0.f);
    for (int f = 0; f < FF; ++f) {
        f2 wqs = mkf2(Wq[f * UU + lane], Ws[f * UU + lane]);
#pragma unroll
        for (int j = 0; j < 4; ++j) {
            float xv = xs[w][j][f];
            aqs[j] += mkf2(xv, xv) * wqs;
        }
    }
    float bql = bq[lane], bsl = bs[lane];
    float as_[4];
#pragma unroll
    for (int j = 0; j < 4; ++j) {
        as_[j] = aqs[j].y + bsl;
        qs[w][j][lane] = (aqs[j].x + bql) * SCALE_F;
    }
    __syncthreads();                          // B (uniform)

    bool mg[4];
#pragma unroll
    for (int j = 0; j < 4; ++j) mg[j] = (xs[w][j][58] != 0.0f);

    const unsigned char* mb = maskb + (size_t)b * NN;
    const u16* kb = kbuf + (size_t)b * NN * UU;
    const u16* vb = vbuf + (size_t)b * NN * UU;
    int nb = gb - b * NN;                     // node base within batch

    // virtual concatenated span over the 4 nodes' bins
    int cum[5]; cum[0] = 0;
    int ebase[4];
#pragma unroll
    for (int j = 0; j < 4; ++j) {
        int dg = counts[nb + j];
        dg = min(max(dg, 0), cap);
        if (!mg[j]) dg = 0;                   // masked dst: skip entire bin
        cum[j + 1] = cum[j] + dg;
        ebase[j] = (nb + j) * cap - cum[j];   // bins addr = ebase[j] + i
    }
    int total = cum[4];

    // accumulators: lane hl holds channels (2hl, 2hl+1) of its half's slots
    f2 acc[4]; float l[4];
#pragma unroll
    for (int j = 0; j < 4; ++j) { acc[j] = mkf2(0.f, 0.f); l[j] = 0.f; }

    const unsigned* vbw = (const unsigned*)vb; // bf16 channel-pair view

#pragma unroll 1
    for (int tbase = 0; tbase < total; tbase += 64) {
        // ---- phase A: lane = edge in dense union tile
        int i = tbase + lane;
        float p = 0.f; int srow = 0;
        if (i < total) {
            int jl = (i >= cum[1]) + (i >= cum[2]) + (i >= cum[3]);
            int s = bins[ebase[jl] + i];
            if (mb[s]) {
                srow = s;
                const uint4* kp = (const uint4*)(kb + ((size_t)s << 6));
                const float* qrow = &qs[w][0][0] + jl * 68;  // per-lane node q
                f2 d01 = mkf2(0.f, 0.f), d23 = mkf2(0.f, 0.f);
#pragma unroll
                for (int c = 0; c < 8; ++c) {
                    uint4 kk = kp[c];
                    const float4 qa = *(const float4*)&qrow[c * 8];
                    const float4 qc = *(const float4*)&qrow[c * 8 + 4];
                    d01 += bf2f2(kk.x) * mkf2(qa.x, qa.y);   // v_pk_fma_f32
                    d23 += bf2f2(kk.y) * mkf2(qa.z, qa.w);
                    d01 += bf2f2(kk.z) * mkf2(qc.x, qc.y);
                    d23 += bf2f2(kk.w) * mkf2(qc.z, qc.w);
                }
                float sc = (d01.x + d01.y) + (d23.x + d23.y);
                p = __expf(sc);               // no-max softmax: scores ~N(0,1)
            }
        }
        pl[w][lane] = ((u64)(unsigned)srow << 32) | (u64)__float_as_uint(p);
        __builtin_amdgcn_wave_barrier();

        // ---- phase B: half-wave slot pairing; lane hl = channels 2hl,2hl+1
#pragma unroll
        for (int j = 0; j < 4; ++j) {
            int lo = max(cum[j], tbase);
            int hi = min(cum[j + 1], tbase + 64);
#pragma unroll 1
            for (int s0 = lo; s0 < hi; s0 += 8) {
#pragma unroll
                for (int k2 = 0; k2 < 4; ++k2) {
                    int ss = s0 + 2 * k2 + hf;
                    int sidx = min(ss, hi - 1) - tbase;
                    u64 pk = pl[w][sidx];     // broadcast per half
                    float pj = (ss < hi) ? u2f((unsigned)pk) : 0.f;
                    unsigned sj = (unsigned)(pk >> 32);
                    unsigned v2 = vbw[(sj << 5) | (unsigned)hl];  // 2 channels
                    acc[j] += mkf2(pj, pj) * bf2f2(v2);           // pk_fma
                    l[j]   += pj;
                }
            }
        }
        __builtin_amdgcn_wave_barrier();
    }

    // finalize: combine halves, remap channel-pair layout -> lane=channel
#pragma unroll
    for (int j = 0; j < 4; ++j) {
        float lj = l[j]      + __shfl_xor(l[j],      32, 64);
        float aE = acc[j].x  + __shfl_xor(acc[j].x,  32, 64);
        float aO = acc[j].y  + __shfl_xor(acc[j].y,  32, 64);
        float vE = __shfl(aE, lane >> 1, 64);
        float vO = __shfl(aO, lane >> 1, 64);
        float a  = (lane & 1) ? vO : vE;
        float agg = (lj > 0.f) ? a / fmaxf(lj, 1e-16f) : 0.f;
        float h2 = mg[j] ? (agg + as_[j]) : xs[w][j][lane];  // masked: pass h
        xs[w][j][lane] = h2;                  // own slot; [64]=xin preserved
    }
    __syncthreads();                          // C (uniform)

    // GRU: value = sigmoid([xin,h2]@W1+b1), c = tanh([xin,r*h2]@W2+b2)
    float xin[4];
#pragma unroll
    for (int j = 0; j < 4; ++j) xin[j] = xs[w][j][64];
    f2 a12[4];                                // {a1, a2} packed
#pragma unroll
    for (int j = 0; j < 4; ++j)
        a12[j] = mkf2(xin[j], xin[j]) * mkf2(W1[lane], W1[UU + lane]);
    for (int f = 0; f < UU; ++f) {
        f2 w12 = mkf2(W1[(f + 1) * 128 + lane], W1[(f + 1) * 128 + UU + lane]);
#pragma unroll
        for (int j = 0; j < 4; ++j) {
            float hv = xs[w][j][f];
            a12[j] += mkf2(hv, hv) * w12;     // v_pk_fma_f32
        }
    }
    float b1a = b1[lane], b1b = b1[UU + lane];
    float z[4];
#pragma unroll
    for (int j = 0; j < 4; ++j) {
        float rst = 1.f / (1.f + __expf(-(a12[j].x + b1a)));
        z[j]      = 1.f / (1.f + __expf(-(a12[j].y + b1b)));
        qs[w][j][lane] = rst * xs[w][j][lane];     // reset*h2
    }
    __syncthreads();                          // D (uniform)

    f2 a3p01 = mkf2(xin[0], xin[1]) * mkf2(W2[lane], W2[lane]);
    f2 a3p23 = mkf2(xin[2], xin[3]) * mkf2(W2[lane], W2[lane]);
    for (int f = 0; f < UU; ++f) {
        float w2v = W2[(f + 1) * UU + lane];
        a3p01 += mkf2(qs[w][0][f], qs[w][1][f]) * mkf2(w2v, w2v);  // pk_fma
        a3p23 += mkf2(qs[w][2][f], qs[w][3][f]) * mkf2(w2v, w2v);
    }
    float b2l = b2[lane];
    float a3v[4] = { a3p01.x, a3p01.y, a3p23.x, a3p23.y };
#pragma unroll
    for (int j = 0; j < 4; ++j) {
        float a = a3v[j] + b2l;
        float aa = fabsf(a), tt = __expf(-2.f * aa);
        float c = copysignf((1.f - tt) / (1.f + tt), a);
        float h2v_ = xs[w][j][lane];
        out[(size_t)(gb + j) * UU + lane] = (1.f - z[j]) * h2v_ + z[j] * c;
    }
}

// ------------------------------------------------------------------- launch
extern "C" void kernel_launch(void* const* d_in, const int* in_sizes, int n_in,
                              void* d_out, int out_size, void* d_ws, size_t ws_size,
                              hipStream_t stream) {
    const float* inputs = (const float*)d_in[0];
    const float* state  = (const float*)d_in[1];
    if (in_sizes[0] != BB * NN) { inputs = (const float*)d_in[1]; state = (const float*)d_in[0]; }
    const int*   esrc   = (const int*)d_in[2];
    const int*   edst   = (const int*)d_in[3];
    const float* Wq = (const float*)d_in[4];
    const float* bq = (const float*)d_in[5];
    const float* Wk = (const float*)d_in[6];
    const float* bk = (const float*)d_in[7];
    const float* Wv = (const float*)d_in[8];
    const float* bv = (const float*)d_in[9];
    const float* Ws = (const float*)d_in[10];
    const float* bs = (const float*)d_in[11];
    const float* W1 = (const float*)d_in[12];
    const float* b1 = (const float*)d_in[13];
    const float* W2 = (const float*)d_in[14];
    const float* b2 = (const float*)d_in[15];
    float* out = (float*)d_out;

    // workspace carve: fixed parts first, bins take the remainder (cap sized
    // from ws_size; cap=64 needs exactly the r8-proven footprint, cap<=128).
    char* base = (char*)d_ws;
    size_t ofs = 0;
    int* counts = (int*)(base + ofs); ofs = align_up(ofs + (size_t)NN * 4);
    unsigned char* maskb = (unsigned char*)(base + ofs); ofs = align_up(ofs + (size_t)BB * NN);
    u16* kbuf = (u16*)(base + ofs); ofs = align_up(ofs + (size_t)BB * NN * UU * 2);
    u16* vbuf = (u16*)(base + ofs); ofs = align_up(ofs + (size_t)BB * NN * UU * 2);
    u16* bins = (u16*)(base + ofs);
    size_t avail = (ws_size > ofs) ? (ws_size - ofs) : 0;
    int cap = (int)(avail / ((size_t)NN * 2));
    if (cap > 128) cap = 128;
    if (cap < 64)  cap = 64;   // r8-proven budget guarantees this fits
    (void)n_in; (void)out_size;

    hipMemsetAsync(counts, 0, (size_t)NN * 4, stream);
    prep_scatter_kernel<<<PREP_BLOCKS + SCAT_BLOCKS, 256, 0, stream>>>(
        state, inputs, Wk, bk, Wv, bv, kbuf, vbuf, maskb,
        edst, esrc, counts, bins, cap);
    fused_fast<<<(BB * NN) / 16, 256, 0, stream>>>(state, inputs, Wq, bq,
                                                   Ws, bs, W1, b1, W2, b2,
                                                   kbuf, vbuf, maskb,
                                                   counts, bins, cap, out);
}

// Round 11
// 336.889 us; speedup vs baseline: 1.1284x; 1.0864x over previous
//
#include <hip/hip_runtime.h>
#include <hip/hip_bf16.h>

// Problem constants (GraphGRUCell_62019327754706)
// DTYPES (settled r4/r5): all float tensors FP32 in and out. int32 edges.
// r6: never clamp launch_bounds waves -> spills.
// r8: 4 nodes/wave @ block=256 => VGPR 64, no spill.
// r9: 8 nodes/wave => spills -> never.
// r11: half-wave node pairing REGRESSED. XCD swizzle WORKED -> keep.
// r12: dense union-range tiling + no-max softmax -> KEEP.
// r13: single-pass padded u16 bins -> total 333, fused 190 (hist. best).
// r14/r15: fp16+fdot2 container-failed TWICE -> fdot2 BLACKLISTED.
// r16-r20: every variant (quarter-wave, unroll4, pk_fma, r13-replica+delta)
//      clusters at fused 224-234 with VALU-busy-time ~CONSTANT (~105us) and
//      stall +45us vs r13 -- including byte-identical edge loops. Suspect
//      ENVIRONMENT shift after the r14/r15 container failures (latency/L2
//      behavior), not the code deltas. r19/r20 attributions unsound.
// r21 (this): byte-exact r13 resubmit to re-anchor. fused~190 -> env fine,
//      r19/r20 changes genuinely bad, iterate from r13 in micro-steps.
//      fused~227 -> env shifted ~20%; r13~r17~r18~r20 within noise; judge
//      all future deltas in-session only.
#define BB 4
#define NN 20000
#define UU 64
#define EE 640000
#define FF 65              // U + D
#define SCALE_F 0.125f     // 1/sqrt(64)
#define PREP_BLOCKS 2500   // (B*N)/32
#define SCAT_BLOCKS 2500   // EE/256

typedef unsigned short u16;
typedef unsigned long long u64;

static inline size_t align_up(size_t x) { return (x + 255) & ~(size_t)255; }

__device__ __forceinline__ float u2f(unsigned int u) { return __uint_as_float(u); }
__device__ __forceinline__ u16 f2bf(float f) {
    __hip_bfloat16 h = __float2bfloat16(f);
    return *reinterpret_cast<u16*>(&h);
}

// ---------------- fat kernel: prep (even blocks) || bin-scatter (odd blocks)
// prep: k,v (bf16) + mask, 8 nodes/wave. scatter: bins[dst*cap+pos]=src.
__global__ __launch_bounds__(256) void prep_scatter_kernel(
    const float* __restrict__ state, const float* __restrict__ inputs,
    const float* __restrict__ Wk, const float* __restrict__ bk,
    const float* __restrict__ Wv, const float* __restrict__ bv,
    u16* __restrict__ kbuf, u16* __restrict__ vbuf,
    unsigned char* __restrict__ maskb,
    const int* __restrict__ edst, const int* __restrict__ esrc,
    int* __restrict__ counts, u16* __restrict__ bins, int cap) {
    int role = blockIdx.x & 1;
    int sub  = blockIdx.x >> 1;
    if (role) {                               // ---- bin-scatter role
        int e = sub * 256 + threadIdx.x;
        if (e < EE) {
            int d = edst[e], s = esrc[e];
            if ((unsigned)d < (unsigned)NN && (unsigned)s < (unsigned)NN) {
                int pos = atomicAdd(&counts[d], 1);
                if (pos < cap) bins[d * cap + pos] = (u16)s;  // clamp: no OOB
            }
        }
        return;
    }
    // ---- prep role
    int w = threadIdx.x >> 6, lane = threadIdx.x & 63;
    int gb = (sub * 4 + w) * 8;               // 8 nodes per wave
    __shared__ float xs[4][8][66];
#pragma unroll
    for (int j = 0; j < 8; ++j) {
        int g = gb + j;
        xs[w][j][lane] = state[(size_t)g * UU + lane];
        if (lane == 0) xs[w][j][64] = inputs[g];
    }
    __syncthreads();                          // uniform (all prep threads reach)

    float ak[8], av[8];
#pragma unroll
    for (int j = 0; j < 8; ++j) { ak[j] = 0.f; av[j] = 0.f; }
    for (int f = 0; f < FF; ++f) {            // weight loaded once, 8 nodes reuse
        float wk = Wk[f * UU + lane], wv = Wv[f * UU + lane];
#pragma unroll
        for (int j = 0; j < 8; ++j) {
            float xv = xs[w][j][f];
            ak[j] += xv * wk; av[j] += xv * wv;
        }
    }
    float bkl = bk[lane], bvl = bv[lane];
#pragma unroll
    for (int j = 0; j < 8; ++j) {
        int g = gb + j;
        kbuf[(size_t)g * UU + lane] = f2bf(ak[j] + bkl);
        vbuf[(size_t)g * UU + lane] = f2bf(av[j] + bvl);
        if (lane == 0) maskb[g] = (xs[w][j][58] != 0.0f) ? 1 : 0;
    }
}

// -------------------- fused: 4 nodes/wave, union tiling over bins, GRU
__global__ __launch_bounds__(256) void fused_fast(
    const float* __restrict__ state, const float* __restrict__ inputs,
    const float* __restrict__ Wq, const float* __restrict__ bq,
    const float* __restrict__ Ws, const float* __restrict__ bs,
    const float* __restrict__ W1, const float* __restrict__ b1,
    const float* __restrict__ W2, const float* __restrict__ b2,
    const u16* __restrict__ kbuf, const u16* __restrict__ vbuf,
    const unsigned char* __restrict__ maskb,
    const int* __restrict__ counts, const u16* __restrict__ bins, int cap,
    float* __restrict__ out) {
    int w = threadIdx.x >> 6, lane = threadIdx.x & 63;
    int hl = lane & 31, hf = lane >> 5;

    // XCD-aware swizzle: batch b pinned to XCDs {2b, 2b+1} (r11: FETCH -29%).
    // grid = 5000 = 625*8, dispatch round-robins XCD = bid%8 -> bijective.
    int bid = blockIdx.x;
    int xcd = bid & 7;
    int b   = xcd >> 1;                            // batch 0..3
    int ib  = ((bid >> 3) << 1) | (xcd & 1);       // block-in-batch 0..1249
    int gb  = b * NN + ib * 16 + w * 4;            // 4 consecutive nodes/wave

    __shared__ float xs[4][4][66];            // x rows; later h2 rows
    __shared__ float qs[4][4][68];            // q rows (68: 4-bank row skew)
    __shared__ u64   pl[4][64];               // per-wave {srow,p} publish

#pragma unroll
    for (int j = 0; j < 4; ++j) {
        int g = gb + j;
        xs[w][j][lane] = state[(size_t)g * UU + lane];
        if (lane == 0) xs[w][j][64] = inputs[g];
    }
    __syncthreads();                          // A (uniform)

    // q (pre-scaled) + sproj for 4 nodes; weight value loaded once
    float aq[4], as_[4];
#pragma unroll
    for (int j = 0; j < 4; ++j) { aq[j] = 0.f; as_[j] = 0.f; }
    for (int f = 0; f < FF; ++f) {
        float wq = Wq[f * UU + lane], ws = Ws[f * UU + lane];
#pragma unroll
        for (int j = 0; j < 4; ++j) {
            float xv = xs[w][j][f];
            aq[j] += xv * wq; as_[j] += xv * ws;
        }
    }
    float bql = bq[lane], bsl = bs[lane];
#pragma unroll
    for (int j = 0; j < 4; ++j) {
        as_[j] += bsl;
        qs[w][j][lane] = (aq[j] + bql) * SCALE_F;
    }
    __syncthreads();                          // B (uniform)

    bool mg[4];
#pragma unroll
    for (int j = 0; j < 4; ++j) mg[j] = (xs[w][j][58] != 0.0f);

    const unsigned char* mb = maskb + (size_t)b * NN;
    const u16* kb = kbuf + (size_t)b * NN * UU;
    const u16* vb = vbuf + (size_t)b * NN * UU;
    int nb = gb - b * NN;                     // node base within batch

    // virtual concatenated span over the 4 nodes' bins
    int cum[5]; cum[0] = 0;
    int ebase[4];
#pragma unroll
    for (int j = 0; j < 4; ++j) {
        int dg = counts[nb + j];
        dg = min(max(dg, 0), cap);
        if (!mg[j]) dg = 0;                   // masked dst: skip entire bin
        cum[j + 1] = cum[j] + dg;
        ebase[j] = (nb + j) * cap - cum[j];   // bins addr = ebase[j] + i
    }
    int total = cum[4];

    // accumulators: lane hl holds channels (2hl, 2hl+1) of its half's slots
    float acE[4], acO[4], l[4];
#pragma unroll
    for (int j = 0; j < 4; ++j) { acE[j] = 0.f; acO[j] = 0.f; l[j] = 0.f; }

    const unsigned* vbw = (const unsigned*)vb; // bf16 channel-pair view

#pragma unroll 1
    for (int tbase = 0; tbase < total; tbase += 64) {
        // ---- phase A: lane = edge in dense union tile
        int i = tbase + lane;
        float p = 0.f; int srow = 0;
        if (i < total) {
            int jl = (i >= cum[1]) + (i >= cum[2]) + (i >= cum[3]);
            int s = bins[ebase[jl] + i];
            if (mb[s]) {
                srow = s;
                const uint4* kp = (const uint4*)(kb + ((size_t)s << 6));
                const float* qrow = &qs[w][0][0] + jl * 68;  // per-lane node q
                float d0 = 0.f, d1 = 0.f, d2 = 0.f, d3 = 0.f;
#pragma unroll
                for (int c = 0; c < 8; ++c) {
                    uint4 kk = kp[c];
                    const float4 qa = *(const float4*)&qrow[c * 8];
                    const float4 qc = *(const float4*)&qrow[c * 8 + 4];
                    d0 += u2f(kk.x << 16) * qa.x; d1 += u2f(kk.x & 0xFFFF0000u) * qa.y;
                    d2 += u2f(kk.y << 16) * qa.z; d3 += u2f(kk.y & 0xFFFF0000u) * qa.w;
                    d0 += u2f(kk.z << 16) * qc.x; d1 += u2f(kk.z & 0xFFFF0000u) * qc.y;
                    d2 += u2f(kk.w << 16) * qc.z; d3 += u2f(kk.w & 0xFFFF0000u) * qc.w;
                }
                float sc = (d0 + d1) + (d2 + d3);
                p = __expf(sc);               // no-max softmax: scores ~N(0,1)
            }
        }
        pl[w][lane] = ((u64)(unsigned)srow << 32) | (u64)__float_as_uint(p);
        __builtin_amdgcn_wave_barrier();

        // ---- phase B: half-wave slot pairing; lane hl = channels 2hl,2hl+1
#pragma unroll
        for (int j = 0; j < 4; ++j) {
            int lo = max(cum[j], tbase);
            int hi = min(cum[j + 1], tbase + 64);
#pragma unroll 1
            for (int s0 = lo; s0 < hi; s0 += 8) {
#pragma unroll
                for (int k2 = 0; k2 < 4; ++k2) {
                    int ss = s0 + 2 * k2 + hf;
                    int sidx = min(ss, hi - 1) - tbase;
                    u64 pk = pl[w][sidx];     // broadcast per half
                    float pj = (ss < hi) ? u2f((unsigned)pk) : 0.f;
                    unsigned sj = (unsigned)(pk >> 32);
                    unsigned v2 = vbw[(sj << 5) | (unsigned)hl];  // 2 channels
                    acE[j] += pj * u2f(v2 << 16);
                    acO[j] += pj * u2f(v2 & 0xFFFF0000u);
                    l[j]   += pj;
                }
            }
        }
        __builtin_amdgcn_wave_barrier();
    }

    // finalize: combine halves, remap channel-pair layout -> lane=channel
#pragma unroll
    for (int j = 0; j < 4; ++j) {
        float lj = l[j]   + __shfl_xor(l[j],   32, 64);
        float aE = acE[j] + __shfl_xor(acE[j], 32, 64);
        float aO = acO[j] + __shfl_xor(acO[j], 32, 64);
        float vE = __shfl(aE, lane >> 1, 64);
        float vO = __shfl(aO, lane >> 1, 64);
        float acc = (lane & 1) ? vO : vE;
        float agg = (lj > 0.f) ? acc / fmaxf(lj, 1e-16f) : 0.f;
        float h2 = mg[j] ? (agg + as_[j]) : xs[w][j][lane];  // masked: pass h
        xs[w][j][lane] = h2;                  // own slot; [64]=xin preserved
    }
    __syncthreads();                          // C (uniform)

    // GRU: value = sigmoid([xin,h2]@W1+b1), c = tanh([xin,r*h2]@W2+b2)
    float xin[4];
#pragma unroll
    for (int j = 0; j < 4; ++j) xin[j] = xs[w][j][64];
    float a1v[4], a2v[4];
#pragma unroll
    for (int j = 0; j < 4; ++j) { a1v[j] = xin[j] * W1[lane]; a2v[j] = xin[j] * W1[UU + lane]; }
    for (int f = 0; f < UU; ++f) {
        float w1a = W1[(f + 1) * 128 + lane], w1b = W1[(f + 1) * 128 + UU + lane];
#pragma unroll
        for (int j = 0; j < 4; ++j) {
            float hv = xs[w][j][f];
            a1v[j] += hv * w1a; a2v[j] += hv * w1b;
        }
    }
    float b1a = b1[lane], b1b = b1[UU + lane];
    float rst[4], z[4];
#pragma unroll
    for (int j = 0; j < 4; ++j) {
        rst[j] = 1.f / (1.f + __expf(-(a1v[j] + b1a)));
        z[j]   = 1.f / (1.f + __expf(-(a2v[j] + b1b)));
        qs[w][j][lane] = rst[j] * xs[w][j][lane];   // reset*h2
    }
    __syncthreads();                          // D (uniform)

    float a3v[4];
#pragma unroll
    for (int j = 0; j < 4; ++j) a3v[j] = xin[j] * W2[lane];
    for (int f = 0; f < UU; ++f) {
        float w2v = W2[(f + 1) * UU + lane];
#pragma unroll
        for (int j = 0; j < 4; ++j) a3v[j] += qs[w][j][f] * w2v;
    }
    float b2l = b2[lane];
#pragma unroll
    for (int j = 0; j < 4; ++j) {
        float a = a3v[j] + b2l;
        float aa = fabsf(a), tt = __expf(-2.f * aa);
        float c = copysignf((1.f - tt) / (1.f + tt), a);
        float h2v_ = xs[w][j][lane];
        out[(size_t)(gb + j) * UU + lane] = (1.f - z[j]) * h2v_ + z[j] * c;
    }
}

// ------------------------------------------------------------------- launch
extern "C" void kernel_launch(void* const* d_in, const int* in_sizes, int n_in,
                              void* d_out, int out_size, void* d_ws, size_t ws_size,
                              hipStream_t stream) {
    const float* inputs = (const float*)d_in[0];
    const float* state  = (const float*)d_in[1];
    if (in_sizes[0] != BB * NN) { inputs = (const float*)d_in[1]; state = (const float*)d_in[0]; }
    const int*   esrc   = (const int*)d_in[2];
    const int*   edst   = (const int*)d_in[3];
    const float* Wq = (const float*)d_in[4];
    const float* bq = (const float*)d_in[5];
    const float* Wk = (const float*)d_in[6];
    const float* bk = (const float*)d_in[7];
    const float* Wv = (const float*)d_in[8];
    const float* bv = (const float*)d_in[9];
    const float* Ws = (const float*)d_in[10];
    const float* bs = (const float*)d_in[11];
    const float* W1 = (const float*)d_in[12];
    const float* b1 = (const float*)d_in[13];
    const float* W2 = (const float*)d_in[14];
    const float* b2 = (const float*)d_in[15];
    float* out = (float*)d_out;

    // workspace carve: fixed parts first, bins take the remainder (cap sized
    // from ws_size; cap=64 needs exactly the r8-proven footprint, cap<=128).
    char* base = (char*)d_ws;
    size_t ofs = 0;
    int* counts = (int*)(base + ofs); ofs = align_up(ofs + (size_t)NN * 4);
    unsigned char* maskb = (unsigned char*)(base + ofs); ofs = align_up(ofs + (size_t)BB * NN);
    u16* kbuf = (u16*)(base + ofs); ofs = align_up(ofs + (size_t)BB * NN * UU * 2);
    u16* vbuf = (u16*)(base + ofs); ofs = align_up(ofs + (size_t)BB * NN * UU * 2);
    u16* bins = (u16*)(base + ofs);
    size_t avail = (ws_size > ofs) ? (ws_size - ofs) : 0;
    int cap = (int)(avail / ((size_t)NN * 2));
    if (cap > 128) cap = 128;
    if (cap < 64)  cap = 64;   // r8-proven budget guarantees this fits
    (void)n_in; (void)out_size;

    hipMemsetAsync(counts, 0, (size_t)NN * 4, stream);
    prep_scatter_kernel<<<PREP_BLOCKS + SCAT_BLOCKS, 256, 0, stream>>>(
        state, inputs, Wk, bk, Wv, bv, kbuf, vbuf, maskb,
        edst, esrc, counts, bins, cap);
    fused_fast<<<(BB * NN) / 16, 256, 0, stream>>>(state, inputs, Wq, bq,
                                                   Ws, bs, W1, b1, W2, b2,
                                                   kbuf, vbuf, maskb,
                                                   counts, bins, cap, out);
}